// Round 8
// baseline (263.977 us; speedup 1.0000x reference)
//
#include <hip/hip_runtime.h>
#include <hip/hip_bf16.h>
#include <math.h>
#include <stdint.h>

#define N_NODES 40000
#define N_EDGES 640000
#define F_IN    512
#define F_OUT   32
#define HEADS   8
#define C_OUT   (HEADS * F_OUT)   // 256
#define NEG_SLOPE 0.2f
#define EPS_F   1e-16f
#define MAXDEG  64                // bucket stride; max in-degree of the fixed
                                  // Poisson(16) graph is ~45 (P(>=64) ~ 1e-12)

typedef __attribute__((ext_vector_type(8)))  short  short8;
typedef __attribute__((ext_vector_type(4)))  short  short4v;
typedef __attribute__((ext_vector_type(16))) float  float16v;

// truncating fp32 -> (hi,lo) bf16 split: hi+lo represents f to ~2^-17 rel
__device__ __forceinline__ void splitT(float f, unsigned short& hi, unsigned short& lo) {
    unsigned u = __float_as_uint(f);
    hi = (unsigned short)(u >> 16);
    float r = f - __uint_as_float(u & 0xFFFF0000u);
    lo = (unsigned short)(__float_as_uint(r) >> 16);
}

__device__ __forceinline__ unsigned short f2bf(float f) {
    unsigned u = __float_as_uint(f);
    return (unsigned short)((u + 0x7FFF + ((u >> 16) & 1)) >> 16);
}

// barrier that does NOT drain vmcnt: LDS visibility needs lgkmcnt(0) only.
// The in-flight HBM prefetch targets a private VGPR -> no cross-wave
// visibility requirement -> letting it ride across the barrier is safe.
// (__syncthreads() would emit s_waitcnt vmcnt(0) and expose full HBM latency.)
#define BARRIER_NOVM() asm volatile("s_waitcnt lgkmcnt(0)\n\ts_barrier" ::: "memory")

// ---------------------------------------------------------------------------
// K0: fused pack_W + cursor zeroing (one launch, independent work).
// Blocks [0,512): pack W into per-lane B-fragment layout for
// mfma_f32_32x32x16_bf16.
// Bp[wc4(4)][ktg(32)][ni(2)][lane(64)][j(8)], value =
//   B[k = ktg*16 + (lane>>5)*8 + j][col = wc4*64 + ni*32 + (lane&31)]
// where B[k][col] = W[col>>5][k][col&31].
// Blocks [512,552): zero the 40000-entry scatter cursor (int4 stores).
// ---------------------------------------------------------------------------
__global__ __launch_bounds__(256) void pack_zero(const float* __restrict__ W,
                                                 unsigned short* __restrict__ Bp,
                                                 int* __restrict__ cursor) {
    if (blockIdx.x < 512) {
        int tid = blockIdx.x * 256 + threadIdx.x;   // 131072 total
        int j    = tid & 7;
        int L    = (tid >> 3) & 63;
        int ni   = (tid >> 9) & 1;
        int ktg  = (tid >> 10) & 31;
        int wc   = tid >> 15;                        // 0..3
        int k    = ktg * 16 + (L >> 5) * 8 + j;
        int col  = wc * 64 + ni * 32 + (L & 31);
        int hh = col >> 5, f = col & 31;
        Bp[tid] = f2bf(W[hh * (F_IN * F_OUT) + k * F_OUT + f]);
    } else {
        int i = (blockIdx.x - 512) * 256 + threadIdx.x;   // 0..10239
        if (i < N_NODES / 4)
            *(int4*)&cursor[i * 4] = (int4){0, 0, 0, 0};
    }
}

// ---------------------------------------------------------------------------
// K1: fused bucket scatter + MFMA projection GEMM.
// Blocks [0,1250): bucket scatter (FIRST in grid -> overlaps the GEMM's
// latency-bound phases instead of forming a serial tail; R7 showed the
// trailing-scatter tail cost ~18 us inside the dispatch).
// Blocks [1250,2500): GEMM. 512 threads = 8 waves, one wave per head;
// tile 32 rows x 256 cols; BK=64. 2-term bf16 split, split accumulators.
// DOUBLE-BUFFERED LDS, ONE barrier per K-step, and the barrier does not
// drain vmcnt (BARRIER_NOVM) -> the HBM prefetch of tile st+2 genuinely
// stays in flight across the barrier (R6/R7 structure drained it at the
// next __syncthreads, exposing ~full HBM latency every K-step).
// Order per step: breg (L2) -> issue HBM st+2 -> convert/write st+1 ->
// MFMA on st -> barrier. In-order vmcnt: waiting on stgB (oldest) leaves
// breg+HBM outstanding; waiting on breg leaves HBM outstanding.
// Epilogue: h16 stores + fused fp32-exact attention scores (head = wc).
// ---------------------------------------------------------------------------
#define AS 66   // k-stride in shorts: 64 + 2 pad (33 banks, odd -> bijection)
#define SCAT_BLOCKS 1250
#define GEMM_BLOCKS 1250

__global__ __launch_bounds__(512, 4) void gemm_scatter(const float* __restrict__ x,
                                                       const unsigned short* __restrict__ Bp,
                                                       const float* __restrict__ a_src,
                                                       const float* __restrict__ a_dst,
                                                       unsigned short* __restrict__ h16,
                                                       float* __restrict__ s_src,
                                                       float* __restrict__ s_dst,
                                                       const int* __restrict__ src,
                                                       const int* __restrict__ dst,
                                                       int* __restrict__ cursor,
                                                       int* __restrict__ src_buf) {
    if (blockIdx.x < SCAT_BLOCKS) {
        int e = blockIdx.x * 512 + threadIdx.x;
        int s = src[e], d = dst[e];
        int pos = atomicAdd(&cursor[d], 1);
        if (pos < MAXDEG) src_buf[d * MAXDEG + pos] = s;
        return;
    }

    __shared__ unsigned short As_hi[2][32 * AS];
    __shared__ unsigned short As_lo[2][32 * AS];

    const int t = threadIdx.x;
    const int wc = t >> 6, L = t & 63;             // wave = head 0..7
    const int r31 = L & 31, half = L >> 5;
    const int n0 = (blockIdx.x - SCAT_BLOCKS) * 32;

    float16v accH, accL;
#pragma unroll
    for (int r = 0; r < 16; ++r) { accH[r] = 0.f; accL[r] = 0.f; }

    // staging: each thread loads ONE float4 (32 rows x 64 k per step)
    const int kcol = (t & 15) * 4;
    const int rbase = t >> 4;        // 0..31
    const float* xp = &x[(size_t)(n0 + rbase) * F_IN + kcol];

    // B fragment base for this wave: wc4 = wc>>1, ni = wc&1
    const unsigned short* bp =
        &Bp[((((size_t)(wc >> 1) * 32) * 2 + (wc & 1)) * 64 + L) * 8];
    // per global k-step ktg: offset ktg*1024 shorts

    // convert a staged float4 -> LDS buffer b
#define CONVW(b, s0) do {                                                      \
        unsigned short h0,h1,h2,h3,l0,l1,l2,l3;                                \
        splitT((s0).x,h0,l0); splitT((s0).y,h1,l1);                            \
        splitT((s0).z,h2,l2); splitT((s0).w,h3,l3);                            \
        int off_ = rbase*AS + kcol;                                            \
        *(short4v*)&As_hi[b][off_] =                                           \
            (short4v){(short)h0,(short)h1,(short)h2,(short)h3};                \
        *(short4v*)&As_lo[b][off_] =                                           \
            (short4v){(short)l0,(short)l1,(short)l2,(short)l3};                \
    } while (0)

    // prologue: tile0 -> LDS[0]; tile1 in flight
    float4 stgB = *(const float4*)(xp);
    CONVW(0, stgB);
    stgB = *(const float4*)(xp + 64);   // tile 1
    BARRIER_NOVM();                     // LDS[0] visible; tile-1 load rides

#pragma unroll
    for (int st = 0; st < 8; ++st) {
        const int cur = st & 1, nxt = cur ^ 1;

        // ---- B fragments first (L2); their wait leaves the HBM load in flight
        short8 breg[4];
#pragma unroll
        for (int kt = 0; kt < 4; ++kt)
            breg[kt] = *(const short8*)(bp + (size_t)(st * 4 + kt) * 1024);

        // ---- issue HBM prefetch of tile st+2 (youngest outstanding load)
        float4 stgC = stgB;
        if (st < 6) stgC = *(const float4*)(xp + (st + 2) * 64);

        // ---- convert + LDS-write tile st+1 into the other buffer
        if (st < 7) CONVW(nxt, stgB);

        // ---- MFMA on tile st from LDS[cur]; two independent term-chains ----
#pragma unroll
        for (int kt = 0; kt < 4; ++kt) {
            int off = r31 * AS + kt * 16 + half * 8;
            short8 ah = *(const short8*)&As_hi[cur][off];
            short8 al = *(const short8*)&As_lo[cur][off];
            accH = __builtin_amdgcn_mfma_f32_32x32x16_bf16(ah, breg[kt], accH, 0, 0, 0);
            accL = __builtin_amdgcn_mfma_f32_32x32x16_bf16(al, breg[kt], accL, 0, 0, 0);
        }

        if (st < 7) BARRIER_NOVM();   // writes to nxt visible; reads of cur done
        stgB = stgC;
    }
#undef CONVW

    // ---- combine the two term-chains ----
#pragma unroll
    for (int r = 0; r < 16; ++r) accH[r] += accL[r];

    // ---- epilogue 1: h16 stores ----
    // C/D layout (32x32): col = lane&31, row = (reg&3) + 8*(reg>>2) + 4*half
    const int colb = wc * 32 + r31;
#pragma unroll
    for (int r = 0; r < 16; ++r) {
        int row = n0 + (r & 3) + 8 * (r >> 2) + 4 * half;
        h16[(size_t)row * C_OUT + colb] = f2bf(accH[r]);
    }

    // ---- epilogue 2: fused attention scores (fp32-exact); head = wc ----
    {
        float af = a_src[wc * 32 + r31];
        float df = a_dst[wc * 32 + r31];
#pragma unroll
        for (int r = 0; r < 16; ++r) {
            float v = accH[r];
            float vs = v * af;
            float vd = v * df;
#pragma unroll
            for (int m = 1; m < 32; m <<= 1) {
                vs += __shfl_xor(vs, m, 64);
                vd += __shfl_xor(vd, m, 64);
            }
            if (r31 == 0) {
                int row = n0 + (r & 3) + 8 * (r >> 2) + 4 * half;
                s_src[row * 8 + wc] = vs;
                s_dst[row * 8 + wc] = vd;
            }
        }
    }
}

// ---------------------------------------------------------------------------
// K6: aggregation. Persistent waves (2048 blocks x 4 waves = 8192 waves),
// each wave strides over ~5 nodes. Bucket CSR: node n's src ids are at
// src_buf[n*64 .. n*64+cnt), cnt = cursor[n].
// EXP-DEDUP: previously all 8 lanes of a head group computed the identical
// score->leaky->exp chain (8x redundant). Now lane (h*8+e) computes ONE
// (edge e, head h) exp and the 8 weights are redistributed by __shfl
// (DS pipe -> off the VALU critical path). 8 exp+leaky+load per lane per
// batch become 1 + 8 shfl.
// ---------------------------------------------------------------------------
__global__ __launch_bounds__(256) void aggregate(const int* __restrict__ src_buf,
                                                 const unsigned short* __restrict__ h16,
                                                 const float* __restrict__ s_src,
                                                 const float* __restrict__ s_dst,
                                                 const int* __restrict__ cursor,
                                                 const float* __restrict__ bias,
                                                 float* __restrict__ out) {
    const int t = threadIdx.x;
    const int wave = t >> 6, lane = t & 63;
    const int wgid = blockIdx.x * 4 + wave;   // 0..8191
    const int ch0 = lane * 4;
    const int hh = lane >> 3;
    const int eL = lane & 7;                  // edge slot this lane exps
    const int gbase = lane & 56;              // head-group base lane

    auto bf2f = [](short v) { return __uint_as_float(((unsigned)(unsigned short)v) << 16); };
    const float4 b4 = *(const float4*)&bias[ch0];

    for (int n = wgid; n < N_NODES; n += 8192) {
        const int start = n * MAXDEG;
        const int cnt = cursor[n];
        const float sd = s_dst[n * 8 + hh];

        float a0 = 0.f, a1 = 0.f, a2 = 0.f, a3 = 0.f, den = 0.f;

        int base = 0;
        // ---- full 8-edge batches ----
        for (; base + 8 <= cnt; base += 8) {
            int idx = start + base;
            int s[8];
#pragma unroll
            for (int u = 0; u < 8; ++u)
                s[u] = src_buf[idx + u];

            short4v v[8];
#pragma unroll
            for (int u = 0; u < 8; ++u)
                v[u] = *(const short4v*)&h16[(size_t)s[u] * C_OUT + ch0];

            // one exp per lane: edge eL, head hh
            float sc = s_src[s[eL] * 8 + hh] + sd;
            sc = sc >= 0.f ? sc : NEG_SLOPE * sc;
            float wx = __expf(sc);

            float w[8];
#pragma unroll
            for (int u = 0; u < 8; ++u)
                w[u] = __shfl(wx, gbase | u, 64);

#pragma unroll
            for (int u = 0; u < 8; ++u) {
                a0 += w[u] * bf2f(v[u][0]);
                a1 += w[u] * bf2f(v[u][1]);
                a2 += w[u] * bf2f(v[u][2]);
                a3 += w[u] * bf2f(v[u][3]);
                den += w[u];
            }
        }

        // ---- masked tail (0..7 edges) ----
        int rem = cnt - base;
        if (rem > 0) {
            int idx = start + base;
            int s[8];
#pragma unroll
            for (int u = 0; u < 8; ++u)
                s[u] = (u < rem) ? src_buf[idx + u] : 0;

            short4v v[8];
#pragma unroll
            for (int u = 0; u < 8; ++u)
                v[u] = *(const short4v*)&h16[(size_t)s[u] * C_OUT + ch0];

            float sc = s_src[s[eL] * 8 + hh] + sd;
            sc = sc >= 0.f ? sc : NEG_SLOPE * sc;
            float wx = __expf(sc);

            float w[8];
#pragma unroll
            for (int u = 0; u < 8; ++u) {
                float ws = __shfl(wx, gbase | u, 64);
                w[u] = (u < rem) ? ws : 0.f;
            }

#pragma unroll
            for (int u = 0; u < 8; ++u) {
                a0 += w[u] * bf2f(v[u][0]);
                a1 += w[u] * bf2f(v[u][1]);
                a2 += w[u] * bf2f(v[u][2]);
                a3 += w[u] * bf2f(v[u][3]);
                den += w[u];
            }
        }

        float inv = 1.0f / (den + EPS_F);
        float4 o;
        o.x = a0 * inv + b4.x;
        o.y = a1 * inv + b4.y;
        o.z = a2 * inv + b4.z;
        o.w = a3 * inv + b4.w;
        *(float4*)&out[(size_t)n * C_OUT + ch0] = o;
    }
}

// ---------------------------------------------------------------------------
extern "C" void kernel_launch(void* const* d_in, const int* in_sizes, int n_in,
                              void* d_out, int out_size, void* d_ws, size_t ws_size,
                              hipStream_t stream) {
    const float* x     = (const float*)d_in[0];
    const int*   eidx  = (const int*)d_in[1];
    const float* W     = (const float*)d_in[2];
    const float* a_src = (const float*)d_in[3];
    const float* a_dst = (const float*)d_in[4];
    const float* bias  = (const float*)d_in[5];
    float* out = (float*)d_out;

    const int* src = eidx;
    const int* dst = eidx + N_EDGES;

    char* p = (char*)d_ws;
    auto carve = [&](size_t bytes) {
        char* r = p;
        p += (bytes + 255) & ~(size_t)255;
        return r;
    };
    unsigned short* h16 = (unsigned short*)carve((size_t)N_NODES * C_OUT * 2);     // 20.48 MB
    float* s_src      = (float*)carve((size_t)N_NODES * HEADS * 4);                // 1.28 MB
    float* s_dst      = (float*)carve((size_t)N_NODES * HEADS * 4);                // 1.28 MB
    int*   src_buf    = (int*)carve((size_t)N_NODES * MAXDEG * 4);                 // 10.24 MB
    int*   cursor     = (int*)carve((size_t)N_NODES * 4);                          // 0.16 MB
    unsigned short* Bp = (unsigned short*)carve((size_t)131072 * 2);               // 0.26 MB

    pack_zero<<<552, 256, 0, stream>>>(W, Bp, cursor);
    gemm_scatter<<<SCAT_BLOCKS + GEMM_BLOCKS, 512, 0, stream>>>(
        x, Bp, a_src, a_dst, h16, s_src, s_dst, src, dst, cursor, src_buf);
    aggregate<<<2048, 256, 0, stream>>>(src_buf, h16, s_src, s_dst,
                                        cursor, bias, out);
}

// Round 9
// 242.087 us; speedup vs baseline: 1.0904x; 1.0904x over previous
//
#include <hip/hip_runtime.h>
#include <hip/hip_bf16.h>
#include <math.h>
#include <stdint.h>

#define N_NODES 40000
#define N_EDGES 640000
#define F_IN    512
#define F_OUT   32
#define HEADS   8
#define C_OUT   (HEADS * F_OUT)   // 256
#define NEG_SLOPE 0.2f
#define EPS_F   1e-16f
#define MAXDEG  64                // bucket stride; max in-degree of the fixed
                                  // Poisson(16) graph is ~45 (P(>=64) ~ 1e-12)

typedef __attribute__((ext_vector_type(8)))  short  short8;
typedef __attribute__((ext_vector_type(4)))  short  short4v;
typedef __attribute__((ext_vector_type(16))) float  float16v;

// truncating fp32 -> (hi,lo) bf16 split: hi+lo represents f to ~2^-17 rel
__device__ __forceinline__ void splitT(float f, unsigned short& hi, unsigned short& lo) {
    unsigned u = __float_as_uint(f);
    hi = (unsigned short)(u >> 16);
    float r = f - __uint_as_float(u & 0xFFFF0000u);
    lo = (unsigned short)(__float_as_uint(r) >> 16);
}

__device__ __forceinline__ unsigned short f2bf(float f) {
    unsigned u = __float_as_uint(f);
    return (unsigned short)((u + 0x7FFF + ((u >> 16) & 1)) >> 16);
}

// barrier that does NOT drain vmcnt: LDS visibility needs lgkmcnt(0) only.
// The in-flight HBM prefetch targets a private VGPR -> no cross-wave
// visibility requirement -> letting it ride across the barrier is safe
// (passed correctness in R8). __syncthreads() would emit s_waitcnt vmcnt(0)
// and expose the full HBM latency of the just-issued prefetch every K-step.
#define BARRIER_NOVM() asm volatile("s_waitcnt lgkmcnt(0)\n\ts_barrier" ::: "memory")

// ---------------------------------------------------------------------------
// K0: fused pack_W + cursor zeroing (one launch, independent work).
// Blocks [0,512): pack W into per-lane B-fragment layout for
// mfma_f32_32x32x16_bf16.
// Bp[wc4(4)][ktg(32)][ni(2)][lane(64)][j(8)], value =
//   B[k = ktg*16 + (lane>>5)*8 + j][col = wc4*64 + ni*32 + (lane&31)]
// where B[k][col] = W[col>>5][k][col&31].
// Blocks [512,552): zero the 40000-entry scatter cursor (int4 stores).
// ---------------------------------------------------------------------------
__global__ __launch_bounds__(256) void pack_zero(const float* __restrict__ W,
                                                 unsigned short* __restrict__ Bp,
                                                 int* __restrict__ cursor) {
    if (blockIdx.x < 512) {
        int tid = blockIdx.x * 256 + threadIdx.x;   // 131072 total
        int j    = tid & 7;
        int L    = (tid >> 3) & 63;
        int ni   = (tid >> 9) & 1;
        int ktg  = (tid >> 10) & 31;
        int wc   = tid >> 15;                        // 0..3
        int k    = ktg * 16 + (L >> 5) * 8 + j;
        int col  = wc * 64 + ni * 32 + (L & 31);
        int hh = col >> 5, f = col & 31;
        Bp[tid] = f2bf(W[hh * (F_IN * F_OUT) + k * F_OUT + f]);
    } else {
        int i = (blockIdx.x - 512) * 256 + threadIdx.x;   // 0..10239
        if (i < N_NODES / 4)
            *(int4*)&cursor[i * 4] = (int4){0, 0, 0, 0};
    }
}

// ---------------------------------------------------------------------------
// K1: fused MFMA projection GEMM + trailing bucket scatter.
// Blocks [0,1250): GEMM (FIRST — R8 showed scatter-at-front serializes ~20us
// ahead of the GEMM; trailing scatter fills the GEMM's drain tail ~free, R7).
// 512 threads = 8 waves, one wave per head; tile 32 rows x 256 cols; BK=64.
// 2-term bf16 split, split accumulators (independent MFMA chains).
// DOUBLE-BUFFERED LDS, ONE barrier per K-step, barrier does NOT drain vmcnt
// (BARRIER_NOVM) -> the HBM prefetch of tile st+2 stays in flight across the
// barrier. Order per step: breg (L2) -> issue HBM st+2 -> convert/write st+1
// -> MFMA on st -> barrier. In-order vmcnt: waiting on stgB (oldest) leaves
// breg+HBM outstanding; waiting on breg leaves the HBM prefetch outstanding.
// Blocks [1250,2500): bucket scatter — pos = atomicAdd(cursor[d]); write src
// id into src_buf[d*64+pos]; cursor doubles as in-degree count.
// Epilogue: h16 stores + fused fp32-exact attention scores (head = wc).
// ---------------------------------------------------------------------------
#define AS 66   // k-stride in shorts: 64 + 2 pad (33 banks, odd -> bijection)
#define GEMM_BLOCKS 1250
#define SCAT_BLOCKS 1250

__global__ __launch_bounds__(512, 4) void gemm_scatter(const float* __restrict__ x,
                                                       const unsigned short* __restrict__ Bp,
                                                       const float* __restrict__ a_src,
                                                       const float* __restrict__ a_dst,
                                                       unsigned short* __restrict__ h16,
                                                       float* __restrict__ s_src,
                                                       float* __restrict__ s_dst,
                                                       const int* __restrict__ src,
                                                       const int* __restrict__ dst,
                                                       int* __restrict__ cursor,
                                                       int* __restrict__ src_buf) {
    if (blockIdx.x >= GEMM_BLOCKS) {
        int e = (blockIdx.x - GEMM_BLOCKS) * 512 + threadIdx.x;
        int s = src[e], d = dst[e];
        int pos = atomicAdd(&cursor[d], 1);
        if (pos < MAXDEG) src_buf[d * MAXDEG + pos] = s;
        return;
    }

    __shared__ unsigned short As_hi[2][32 * AS];
    __shared__ unsigned short As_lo[2][32 * AS];

    const int t = threadIdx.x;
    const int wc = t >> 6, L = t & 63;             // wave = head 0..7
    const int r31 = L & 31, half = L >> 5;
    const int n0 = blockIdx.x * 32;

    float16v accH, accL;
#pragma unroll
    for (int r = 0; r < 16; ++r) { accH[r] = 0.f; accL[r] = 0.f; }

    // staging: each thread loads ONE float4 (32 rows x 64 k per step)
    const int kcol = (t & 15) * 4;
    const int rbase = t >> 4;        // 0..31
    const float* xp = &x[(size_t)(n0 + rbase) * F_IN + kcol];

    // B fragment base for this wave: wc4 = wc>>1, ni = wc&1
    const unsigned short* bp =
        &Bp[((((size_t)(wc >> 1) * 32) * 2 + (wc & 1)) * 64 + L) * 8];
    // per global k-step ktg: offset ktg*1024 shorts

    // convert a staged float4 -> LDS buffer b
#define CONVW(b, s0) do {                                                      \
        unsigned short h0,h1,h2,h3,l0,l1,l2,l3;                                \
        splitT((s0).x,h0,l0); splitT((s0).y,h1,l1);                            \
        splitT((s0).z,h2,l2); splitT((s0).w,h3,l3);                            \
        int off_ = rbase*AS + kcol;                                            \
        *(short4v*)&As_hi[b][off_] =                                           \
            (short4v){(short)h0,(short)h1,(short)h2,(short)h3};                \
        *(short4v*)&As_lo[b][off_] =                                           \
            (short4v){(short)l0,(short)l1,(short)l2,(short)l3};                \
    } while (0)

    // prologue: issue tile0 AND tile1 (both in flight) before converting
    // tile0 — the convert's vmcnt wait targets tile0 only (in-order, older),
    // leaving tile1 riding into the loop.
    float4 stgA = *(const float4*)(xp);        // tile 0
    float4 stgB = *(const float4*)(xp + 64);   // tile 1
    CONVW(0, stgA);
    BARRIER_NOVM();                            // LDS[0] visible; tile-1 rides

#pragma unroll
    for (int st = 0; st < 8; ++st) {
        const int cur = st & 1, nxt = cur ^ 1;

        // ---- B fragments first (L2); their wait leaves the HBM load in flight
        short8 breg[4];
#pragma unroll
        for (int kt = 0; kt < 4; ++kt)
            breg[kt] = *(const short8*)(bp + (size_t)(st * 4 + kt) * 1024);

        // ---- issue HBM prefetch of tile st+2 (youngest outstanding load)
        float4 stgC = stgB;
        if (st < 6) stgC = *(const float4*)(xp + (st + 2) * 64);

        // ---- convert + LDS-write tile st+1 into the other buffer
        if (st < 7) CONVW(nxt, stgB);

        // ---- MFMA on tile st from LDS[cur]; two independent term-chains ----
#pragma unroll
        for (int kt = 0; kt < 4; ++kt) {
            int off = r31 * AS + kt * 16 + half * 8;
            short8 ah = *(const short8*)&As_hi[cur][off];
            short8 al = *(const short8*)&As_lo[cur][off];
            accH = __builtin_amdgcn_mfma_f32_32x32x16_bf16(ah, breg[kt], accH, 0, 0, 0);
            accL = __builtin_amdgcn_mfma_f32_32x32x16_bf16(al, breg[kt], accL, 0, 0, 0);
        }

        if (st < 7) BARRIER_NOVM();   // writes to nxt visible; reads of cur done
        stgB = stgC;
    }
#undef CONVW

    // ---- combine the two term-chains ----
#pragma unroll
    for (int r = 0; r < 16; ++r) accH[r] += accL[r];

    // ---- epilogue 1: h16 stores ----
    // C/D layout (32x32): col = lane&31, row = (reg&3) + 8*(reg>>2) + 4*half
    const int colb = wc * 32 + r31;
#pragma unroll
    for (int r = 0; r < 16; ++r) {
        int row = n0 + (r & 3) + 8 * (r >> 2) + 4 * half;
        h16[(size_t)row * C_OUT + colb] = f2bf(accH[r]);
    }

    // ---- epilogue 2: fused attention scores (fp32-exact); head = wc ----
    {
        float af = a_src[wc * 32 + r31];
        float df = a_dst[wc * 32 + r31];
#pragma unroll
        for (int r = 0; r < 16; ++r) {
            float v = accH[r];
            float vs = v * af;
            float vd = v * df;
#pragma unroll
            for (int m = 1; m < 32; m <<= 1) {
                vs += __shfl_xor(vs, m, 64);
                vd += __shfl_xor(vd, m, 64);
            }
            if (r31 == 0) {
                int row = n0 + (r & 3) + 8 * (r >> 2) + 4 * half;
                s_src[row * 8 + wc] = vs;
                s_dst[row * 8 + wc] = vd;
            }
        }
    }
}

// ---------------------------------------------------------------------------
// K6: aggregation. Persistent waves (2048 blocks x 4 waves = 8192 waves),
// each wave strides over ~5 nodes. Bucket CSR: node n's src ids are at
// src_buf[n*64 .. n*64+cnt), cnt = cursor[n].
// EXP-DEDUP: lane (h*8+e) computes ONE (edge e, head h) exp; the 8 weights
// are redistributed by __shfl (DS pipe, off the VALU critical path).
// ---------------------------------------------------------------------------
__global__ __launch_bounds__(256) void aggregate(const int* __restrict__ src_buf,
                                                 const unsigned short* __restrict__ h16,
                                                 const float* __restrict__ s_src,
                                                 const float* __restrict__ s_dst,
                                                 const int* __restrict__ cursor,
                                                 const float* __restrict__ bias,
                                                 float* __restrict__ out) {
    const int t = threadIdx.x;
    const int wave = t >> 6, lane = t & 63;
    const int wgid = blockIdx.x * 4 + wave;   // 0..8191
    const int ch0 = lane * 4;
    const int hh = lane >> 3;
    const int eL = lane & 7;                  // edge slot this lane exps
    const int gbase = lane & 56;              // head-group base lane

    auto bf2f = [](short v) { return __uint_as_float(((unsigned)(unsigned short)v) << 16); };
    const float4 b4 = *(const float4*)&bias[ch0];

    for (int n = wgid; n < N_NODES; n += 8192) {
        const int start = n * MAXDEG;
        const int cnt = cursor[n];
        const float sd = s_dst[n * 8 + hh];

        float a0 = 0.f, a1 = 0.f, a2 = 0.f, a3 = 0.f, den = 0.f;

        int base = 0;
        // ---- full 8-edge batches ----
        for (; base + 8 <= cnt; base += 8) {
            int idx = start + base;
            int s[8];
#pragma unroll
            for (int u = 0; u < 8; ++u)
                s[u] = src_buf[idx + u];

            short4v v[8];
#pragma unroll
            for (int u = 0; u < 8; ++u)
                v[u] = *(const short4v*)&h16[(size_t)s[u] * C_OUT + ch0];

            // one exp per lane: edge eL, head hh
            float sc = s_src[s[eL] * 8 + hh] + sd;
            sc = sc >= 0.f ? sc : NEG_SLOPE * sc;
            float wx = __expf(sc);

            float w[8];
#pragma unroll
            for (int u = 0; u < 8; ++u)
                w[u] = __shfl(wx, gbase | u, 64);

#pragma unroll
            for (int u = 0; u < 8; ++u) {
                a0 += w[u] * bf2f(v[u][0]);
                a1 += w[u] * bf2f(v[u][1]);
                a2 += w[u] * bf2f(v[u][2]);
                a3 += w[u] * bf2f(v[u][3]);
                den += w[u];
            }
        }

        // ---- masked tail (0..7 edges) ----
        int rem = cnt - base;
        if (rem > 0) {
            int idx = start + base;
            int s[8];
#pragma unroll
            for (int u = 0; u < 8; ++u)
                s[u] = (u < rem) ? src_buf[idx + u] : 0;

            short4v v[8];
#pragma unroll
            for (int u = 0; u < 8; ++u)
                v[u] = *(const short4v*)&h16[(size_t)s[u] * C_OUT + ch0];

            float sc = s_src[s[eL] * 8 + hh] + sd;
            sc = sc >= 0.f ? sc : NEG_SLOPE * sc;
            float wx = __expf(sc);

            float w[8];
#pragma unroll
            for (int u = 0; u < 8; ++u) {
                float ws = __shfl(wx, gbase | u, 64);
                w[u] = (u < rem) ? ws : 0.f;
            }

#pragma unroll
            for (int u = 0; u < 8; ++u) {
                a0 += w[u] * bf2f(v[u][0]);
                a1 += w[u] * bf2f(v[u][1]);
                a2 += w[u] * bf2f(v[u][2]);
                a3 += w[u] * bf2f(v[u][3]);
                den += w[u];
            }
        }

        float inv = 1.0f / (den + EPS_F);
        float4 o;
        o.x = a0 * inv + b4.x;
        o.y = a1 * inv + b4.y;
        o.z = a2 * inv + b4.z;
        o.w = a3 * inv + b4.w;
        *(float4*)&out[(size_t)n * C_OUT + ch0] = o;
    }
}

// ---------------------------------------------------------------------------
extern "C" void kernel_launch(void* const* d_in, const int* in_sizes, int n_in,
                              void* d_out, int out_size, void* d_ws, size_t ws_size,
                              hipStream_t stream) {
    const float* x     = (const float*)d_in[0];
    const int*   eidx  = (const int*)d_in[1];
    const float* W     = (const float*)d_in[2];
    const float* a_src = (const float*)d_in[3];
    const float* a_dst = (const float*)d_in[4];
    const float* bias  = (const float*)d_in[5];
    float* out = (float*)d_out;

    const int* src = eidx;
    const int* dst = eidx + N_EDGES;

    char* p = (char*)d_ws;
    auto carve = [&](size_t bytes) {
        char* r = p;
        p += (bytes + 255) & ~(size_t)255;
        return r;
    };
    unsigned short* h16 = (unsigned short*)carve((size_t)N_NODES * C_OUT * 2);     // 20.48 MB
    float* s_src      = (float*)carve((size_t)N_NODES * HEADS * 4);                // 1.28 MB
    float* s_dst      = (float*)carve((size_t)N_NODES * HEADS * 4);                // 1.28 MB
    int*   src_buf    = (int*)carve((size_t)N_NODES * MAXDEG * 4);                 // 10.24 MB
    int*   cursor     = (int*)carve((size_t)N_NODES * 4);                          // 0.16 MB
    unsigned short* Bp = (unsigned short*)carve((size_t)131072 * 2);               // 0.26 MB

    pack_zero<<<552, 256, 0, stream>>>(W, Bp, cursor);
    gemm_scatter<<<GEMM_BLOCKS + SCAT_BLOCKS, 512, 0, stream>>>(
        x, Bp, a_src, a_dst, h16, s_src, s_dst, src, dst, cursor, src_buf);
    aggregate<<<2048, 256, 0, stream>>>(src_buf, h16, s_src, s_dst,
                                        cursor, bias, out);
}